// Round 7
// baseline (308.937 us; speedup 1.0000x reference)
//
#include <hip/hip_runtime.h>
#include <math.h>

#define BS   64
#define CH   256
#define NPIX 3136        // 56*56
#define NK   3
#define P    64          // pixels per block tile
#define NT   49          // 3136 / 64, exact

// ws layout (floats): sa then qx
#define WS_SA 0
#define WS_QX (BS*NK)

// ---------------------------------------------------------------------------
// Fused kernel, low-LDS variant: phase A computes soft assignment from
// coalesced loads; phase B RE-LOADS the same addresses (L1/L2-hot) and
// reduce-scatters the pooled partials across each 16-lane group.
// Thread layout: pq = tid&15 (pixel quad: pixels 4pq..4pq+3),
//                cc = tid>>4 (channel residue: channels 16i+cc, i=0..15).
// ---------------------------------------------------------------------------
__global__ __launch_bounds__(256)
void pgn_main(const float* __restrict__ x,        // [BS][CH][NPIX]
              const float* __restrict__ centers,  // [NK][CH]
              const float* __restrict__ psf,      // [NK]
              float* __restrict__ assign_out,     // [BS][NK][NPIX]
              float* __restrict__ sa,             // [BS][NK]      (zeroed)
              float* __restrict__ qx)             // [BS][NK][CH]  (zeroed)
{
    __shared__ float4 ctr_sh[CH];        // 4 KB
    __shared__ float  part[4][16][16];   // 4 KB  phase-A partial dots
    __shared__ float  a_sh[NK][P];       // 768 B
    __shared__ float  cred[4][NK];
    __shared__ float  csq_sh[NK];

    const int tid  = threadIdx.x;
    const int b    = blockIdx.x / NT;
    const int t    = blockIdx.x % NT;
    const int n0   = t * P;
    const int pq   = tid & 15;
    const int cc   = tid >> 4;
    const int lane = tid & 63;
    const int w    = tid >> 6;

    // ---- centers transpose + c_sq ----
    {
        const float c0 = centers[tid], c1 = centers[CH + tid], c2 = centers[2*CH + tid];
        ctr_sh[tid] = make_float4(c0, c1, c2, 0.f);
        float s0 = c0*c0, s1 = c1*c1, s2 = c2*c2;
        #pragma unroll
        for (int m = 32; m; m >>= 1) {
            s0 += __shfl_xor(s0, m, 64);
            s1 += __shfl_xor(s1, m, 64);
            s2 += __shfl_xor(s2, m, 64);
        }
        if (lane == 0) { cred[w][0] = s0; cred[w][1] = s1; cred[w][2] = s2; }
    }
    __syncthreads();
    if (tid < NK) csq_sh[tid] = cred[0][tid] + cred[1][tid] + cred[2][tid] + cred[3][tid];

    // ---- Phase A: coalesced float4 loads, center-dot partials in regs ----
    float cxa[NK][4], xsq[4];
    #pragma unroll
    for (int j = 0; j < 4; ++j) { cxa[0][j]=0.f; cxa[1][j]=0.f; cxa[2][j]=0.f; xsq[j]=0.f; }

    const float* xb = x + (size_t)b * CH * NPIX + (n0 + 4*pq);
    #pragma unroll
    for (int i = 0; i < 16; ++i) {
        const int c = 16*i + cc;
        const float4 xv = *(const float4*)(xb + (size_t)c * NPIX);
        const float4 cv = ctr_sh[c];
        const float xj[4] = {xv.x, xv.y, xv.z, xv.w};
        #pragma unroll
        for (int j = 0; j < 4; ++j) {
            cxa[0][j] = fmaf(cv.x, xj[j], cxa[0][j]);
            cxa[1][j] = fmaf(cv.y, xj[j], cxa[1][j]);
            cxa[2][j] = fmaf(cv.z, xj[j], cxa[2][j]);
            xsq[j]    = fmaf(xj[j], xj[j], xsq[j]);
        }
    }

    // reduce over the wave's 4 channel-chunks (lanes l, l^16, l^32, l^48)
    #pragma unroll
    for (int j = 0; j < 4; ++j) {
        #pragma unroll
        for (int k = 0; k < NK; ++k) {
            cxa[k][j] += __shfl_xor(cxa[k][j], 16, 64);
            cxa[k][j] += __shfl_xor(cxa[k][j], 32, 64);
        }
        xsq[j] += __shfl_xor(xsq[j], 16, 64);
        xsq[j] += __shfl_xor(xsq[j], 32, 64);
    }
    if ((tid & 48) == 0) {   // lanes 0..15 of each wave hold the wave sums
        float* pp = &part[w][pq][0];
        #pragma unroll
        for (int j = 0; j < 4; ++j) {
            pp[j]      = cxa[0][j];
            pp[4 + j]  = cxa[1][j];
            pp[8 + j]  = cxa[2][j];
            pp[12 + j] = xsq[j];
        }
    }
    __syncthreads();   // part, csq_sh ready

    // ---- softmax for the 64 pixels (wave 0) ----
    if (tid < P) {
        const int p = tid, q = p >> 2, r = p & 3;
        float cx0 = 0.f, cx1 = 0.f, cx2 = 0.f, xs = 0.f;
        #pragma unroll
        for (int ww = 0; ww < 4; ++ww) {
            cx0 += part[ww][q][r];
            cx1 += part[ww][q][4 + r];
            cx2 += part[ww][q][8 + r];
            xs  += part[ww][q][12 + r];
        }
        const float rb0 = 1.f + __expf(-psf[0]);
        const float rb1 = 1.f + __expf(-psf[1]);
        const float rb2 = 1.f + __expf(-psf[2]);
        const float l0 = fminf(2.f*cx0 - xs - csq_sh[0], 0.f) * rb0;
        const float l1 = fminf(2.f*cx1 - xs - csq_sh[1], 0.f) * rb1;
        const float l2 = fminf(2.f*cx2 - xs - csq_sh[2], 0.f) * rb2;
        const float m  = fmaxf(l0, fmaxf(l1, l2));
        const float e0 = __expf(l0 - m), e1 = __expf(l1 - m), e2 = __expf(l2 - m);
        const float inv = 1.f / (e0 + e1 + e2);
        const float a0 = e0*inv, a1 = e1*inv, a2 = e2*inv;

        a_sh[0][p] = a0; a_sh[1][p] = a1; a_sh[2][p] = a2;

        float* ao = assign_out + (size_t)b * NK * NPIX + n0 + p;
        ao[0]        = a0;
        ao[NPIX]     = a1;
        ao[2*NPIX]   = a2;

        float s0 = a0, s1 = a1, s2 = a2;
        #pragma unroll
        for (int m2 = 32; m2; m2 >>= 1) {
            s0 += __shfl_xor(s0, m2, 64);
            s1 += __shfl_xor(s1, m2, 64);
            s2 += __shfl_xor(s2, m2, 64);
        }
        if (tid == 0) {
            atomicAdd(&sa[b*NK + 0], s0);
            atomicAdd(&sa[b*NK + 1], s1);
            atomicAdd(&sa[b*NK + 2], s2);
        }
    }
    __syncthreads();   // a_sh ready

    // ---- Phase B: re-load x (same addresses, cache-hot), accumulate
    //      q[i][k] = sum_j a[k][4pq+j] * x[16i+cc][4pq+j]. ----
    float ar[NK][4];
    #pragma unroll
    for (int k = 0; k < NK; ++k)
        #pragma unroll
        for (int j = 0; j < 4; ++j) ar[k][j] = a_sh[k][4*pq + j];

    float q[16][NK];
    #pragma unroll
    for (int i = 0; i < 16; ++i) {
        const int c = 16*i + cc;
        const float4 xv = *(const float4*)(xb + (size_t)c * NPIX);
        q[i][0] = fmaf(ar[0][0], xv.x, fmaf(ar[0][1], xv.y, fmaf(ar[0][2], xv.z, ar[0][3]*xv.w)));
        q[i][1] = fmaf(ar[1][0], xv.x, fmaf(ar[1][1], xv.y, fmaf(ar[1][2], xv.z, ar[1][3]*xv.w)));
        q[i][2] = fmaf(ar[2][0], xv.x, fmaf(ar[2][1], xv.y, fmaf(ar[2][2], xv.z, ar[2][3]*xv.w)));
    }

    // ---- reduce-scatter over the 16-lane pq-group (masks 1,2,4,8 stay
    //      within the group). After step s, slot j holds channel
    //      i = j*2^s + (pq & (2^s-1)); finally lane pq holds i = pq. ----
    const bool b0 = (pq & 1) != 0;
    float c1v[8][NK];
    #pragma unroll
    for (int u = 0; u < 8; ++u)
        #pragma unroll
        for (int k = 0; k < NK; ++k) {
            const float send = b0 ? q[2*u][k]   : q[2*u+1][k];
            const float keep = b0 ? q[2*u+1][k] : q[2*u][k];
            c1v[u][k] = keep + __shfl_xor(send, 1, 64);
        }
    const bool b1 = (pq & 2) != 0;
    float c2v[4][NK];
    #pragma unroll
    for (int u = 0; u < 4; ++u)
        #pragma unroll
        for (int k = 0; k < NK; ++k) {
            const float send = b1 ? c1v[2*u][k]   : c1v[2*u+1][k];
            const float keep = b1 ? c1v[2*u+1][k] : c1v[2*u][k];
            c2v[u][k] = keep + __shfl_xor(send, 2, 64);
        }
    const bool b2 = (pq & 4) != 0;
    float c3v[2][NK];
    #pragma unroll
    for (int u = 0; u < 2; ++u)
        #pragma unroll
        for (int k = 0; k < NK; ++k) {
            const float send = b2 ? c2v[2*u][k]   : c2v[2*u+1][k];
            const float keep = b2 ? c2v[2*u+1][k] : c2v[2*u][k];
            c3v[u][k] = keep + __shfl_xor(send, 4, 64);
        }
    const bool b3 = (pq & 8) != 0;
    float r[NK];
    #pragma unroll
    for (int k = 0; k < NK; ++k) {
        const float send = b3 ? c3v[0][k] : c3v[1][k];
        const float keep = b3 ? c3v[1][k] : c3v[0][k];
        r[k] = keep + __shfl_xor(send, 8, 64);
    }

    // lane (pq,cc) now holds totals for channel c_out = 16*pq + cc
    const int c_out = 16*pq + cc;
    float* qb = qx + (size_t)b * NK * CH + c_out;
    atomicAdd(qb,        r[0]);
    atomicAdd(qb + CH,   r[1]);
    atomicAdd(qb + 2*CH, r[2]);
}

// ---------------------------------------------------------------------------
// Finalize: qx/sum_ass, subtract centers, /sigma, L2-normalize over channels,
// transposed store to outputs[b][c][k].
// ---------------------------------------------------------------------------
__global__ __launch_bounds__(256)
void pgn_final(const float* __restrict__ qx,       // [BS][NK][CH]
               const float* __restrict__ sa,       // [BS][NK]
               const float* __restrict__ centers,  // [NK][CH]
               const float* __restrict__ psf,      // [NK]
               float* __restrict__ out)            // [BS][CH][NK]
{
    const int b = blockIdx.x;
    const int c = threadIdx.x;
    const int wave = c >> 6, lane = c & 63;
    __shared__ float red[4][NK];
    __shared__ float nrm[NK];

    float v[NK], ss[NK];
    #pragma unroll
    for (int k = 0; k < NK; ++k) {
        const float beta = 1.f / (1.f + __expf(-psf[k]));
        const float sig  = sqrtf(0.5f * beta);
        const float s    = fmaxf(sa[b*NK + k], 1e-5f);
        const float q    = qx[((size_t)b*NK + k)*CH + c] / s;
        v[k]  = (q - centers[k*CH + c]) / sig;
        ss[k] = v[k] * v[k];
    }
    #pragma unroll
    for (int m = 32; m; m >>= 1) {
        ss[0] += __shfl_xor(ss[0], m, 64);
        ss[1] += __shfl_xor(ss[1], m, 64);
        ss[2] += __shfl_xor(ss[2], m, 64);
    }
    if (lane == 0) { red[wave][0] = ss[0]; red[wave][1] = ss[1]; red[wave][2] = ss[2]; }
    __syncthreads();
    if (c < NK) {
        const float tot = red[0][c] + red[1][c] + red[2][c] + red[3][c];
        nrm[c] = fmaxf(sqrtf(tot), 1e-12f);
    }
    __syncthreads();
    float* o = out + ((size_t)b*CH + c)*NK;
    #pragma unroll
    for (int k = 0; k < NK; ++k) o[k] = v[k] / nrm[k];
}

// ---------------------------------------------------------------------------
extern "C" void kernel_launch(void* const* d_in, const int* in_sizes, int n_in,
                              void* d_out, int out_size, void* d_ws, size_t ws_size,
                              hipStream_t stream)
{
    const float* feat    = (const float*)d_in[0];
    const float* centers = (const float*)d_in[1];
    const float* psf     = (const float*)d_in[2];

    float* out        = (float*)d_out;            // [BS][CH][NK] first
    float* assign_out = out + (size_t)BS*CH*NK;   // then [BS][NK][NPIX]

    float* sa = (float*)d_ws + WS_SA;             // [BS][NK]
    float* qx = (float*)d_ws + WS_QX;             // [BS][NK][CH]

    // zero the atomic accumulators (ws is poisoned 0xAA before every launch)
    hipMemsetAsync(d_ws, 0, (BS*NK + BS*NK*CH) * sizeof(float), stream);

    pgn_main<<<dim3(BS*NT), dim3(256), 0, stream>>>(
        feat, centers, psf, assign_out, sa, qx);

    pgn_final<<<dim3(BS), dim3(256), 0, stream>>>(qx, sa, centers, psf, out);
}

// Round 8
// 299.987 us; speedup vs baseline: 1.0298x; 1.0298x over previous
//
#include <hip/hip_runtime.h>
#include <math.h>

#define BS   64
#define CH   256
#define NPIX 3136        // 56*56
#define NK   3
#define P    64          // pixels per block tile
#define NT   49          // 3136 / 64, exact

// ws layout (floats): sa then qx
#define WS_SA 0
#define WS_QX (BS*NK)

// ---------------------------------------------------------------------------
// Fused kernel, register-resident x variant: ALL 16 float4 loads are issued
// back-to-back into registers (max MLP), then phase A computes assignment,
// then phase B pools from the SAME registers (x touched exactly once).
// Thread layout: pq = tid&15 (pixel quad: pixels 4pq..4pq+3),
//                cc = tid>>4 (channel residue: channels 16i+cc, i=0..15).
// ---------------------------------------------------------------------------
__global__ __launch_bounds__(256)
void pgn_main(const float* __restrict__ x,        // [BS][CH][NPIX]
              const float* __restrict__ centers,  // [NK][CH]
              const float* __restrict__ psf,      // [NK]
              float* __restrict__ assign_out,     // [BS][NK][NPIX]
              float* __restrict__ sa,             // [BS][NK]      (zeroed)
              float* __restrict__ qx)             // [BS][NK][CH]  (zeroed)
{
    __shared__ float4 ctr_sh[CH];        // 4 KB
    __shared__ float  part[4][16][16];   // 4 KB  phase-A partial dots
    __shared__ float  a_sh[NK][P];       // 768 B
    __shared__ float  cred[4][NK];
    __shared__ float  csq_sh[NK];

    const int tid  = threadIdx.x;
    const int b    = blockIdx.x / NT;
    const int t    = blockIdx.x % NT;
    const int n0   = t * P;
    const int pq   = tid & 15;
    const int cc   = tid >> 4;
    const int lane = tid & 63;
    const int w    = tid >> 6;

    // ---- issue ALL x loads first: 16 independent float4 loads in flight ----
    float4 xv[16];
    const float* xb = x + (size_t)b * CH * NPIX + (n0 + 4*pq);
    #pragma unroll
    for (int i = 0; i < 16; ++i)
        xv[i] = *(const float4*)(xb + (size_t)(16*i + cc) * NPIX);

    // ---- centers transpose + c_sq (overlaps with x loads in flight) ----
    {
        const float c0 = centers[tid], c1 = centers[CH + tid], c2 = centers[2*CH + tid];
        ctr_sh[tid] = make_float4(c0, c1, c2, 0.f);
        float s0 = c0*c0, s1 = c1*c1, s2 = c2*c2;
        #pragma unroll
        for (int m = 32; m; m >>= 1) {
            s0 += __shfl_xor(s0, m, 64);
            s1 += __shfl_xor(s1, m, 64);
            s2 += __shfl_xor(s2, m, 64);
        }
        if (lane == 0) { cred[w][0] = s0; cred[w][1] = s1; cred[w][2] = s2; }
    }
    __syncthreads();
    if (tid < NK) csq_sh[tid] = cred[0][tid] + cred[1][tid] + cred[2][tid] + cred[3][tid];

    // ---- Phase A: center-dot partials from the register-held x ----
    float cxa[NK][4], xsq[4];
    #pragma unroll
    for (int j = 0; j < 4; ++j) { cxa[0][j]=0.f; cxa[1][j]=0.f; cxa[2][j]=0.f; xsq[j]=0.f; }

    #pragma unroll
    for (int i = 0; i < 16; ++i) {
        const float4 cv = ctr_sh[16*i + cc];
        const float4 v  = xv[i];
        const float xj[4] = {v.x, v.y, v.z, v.w};
        #pragma unroll
        for (int j = 0; j < 4; ++j) {
            cxa[0][j] = fmaf(cv.x, xj[j], cxa[0][j]);
            cxa[1][j] = fmaf(cv.y, xj[j], cxa[1][j]);
            cxa[2][j] = fmaf(cv.z, xj[j], cxa[2][j]);
            xsq[j]    = fmaf(xj[j], xj[j], xsq[j]);
        }
    }

    // reduce over the wave's 4 channel-chunks (lanes l, l^16, l^32, l^48)
    #pragma unroll
    for (int j = 0; j < 4; ++j) {
        #pragma unroll
        for (int k = 0; k < NK; ++k) {
            cxa[k][j] += __shfl_xor(cxa[k][j], 16, 64);
            cxa[k][j] += __shfl_xor(cxa[k][j], 32, 64);
        }
        xsq[j] += __shfl_xor(xsq[j], 16, 64);
        xsq[j] += __shfl_xor(xsq[j], 32, 64);
    }
    if ((tid & 48) == 0) {   // lanes 0..15 of each wave hold the wave sums
        float* pp = &part[w][pq][0];
        #pragma unroll
        for (int j = 0; j < 4; ++j) {
            pp[j]      = cxa[0][j];
            pp[4 + j]  = cxa[1][j];
            pp[8 + j]  = cxa[2][j];
            pp[12 + j] = xsq[j];
        }
    }
    __syncthreads();   // part, csq_sh ready

    // ---- softmax for the 64 pixels (wave 0) ----
    if (tid < P) {
        const int p = tid, q = p >> 2, r = p & 3;
        float cx0 = 0.f, cx1 = 0.f, cx2 = 0.f, xs = 0.f;
        #pragma unroll
        for (int ww = 0; ww < 4; ++ww) {
            cx0 += part[ww][q][r];
            cx1 += part[ww][q][4 + r];
            cx2 += part[ww][q][8 + r];
            xs  += part[ww][q][12 + r];
        }
        const float rb0 = 1.f + __expf(-psf[0]);
        const float rb1 = 1.f + __expf(-psf[1]);
        const float rb2 = 1.f + __expf(-psf[2]);
        const float l0 = fminf(2.f*cx0 - xs - csq_sh[0], 0.f) * rb0;
        const float l1 = fminf(2.f*cx1 - xs - csq_sh[1], 0.f) * rb1;
        const float l2 = fminf(2.f*cx2 - xs - csq_sh[2], 0.f) * rb2;
        const float m  = fmaxf(l0, fmaxf(l1, l2));
        const float e0 = __expf(l0 - m), e1 = __expf(l1 - m), e2 = __expf(l2 - m);
        const float inv = 1.f / (e0 + e1 + e2);
        const float a0 = e0*inv, a1 = e1*inv, a2 = e2*inv;

        a_sh[0][p] = a0; a_sh[1][p] = a1; a_sh[2][p] = a2;

        float* ao = assign_out + (size_t)b * NK * NPIX + n0 + p;
        ao[0]        = a0;
        ao[NPIX]     = a1;
        ao[2*NPIX]   = a2;

        float s0 = a0, s1 = a1, s2 = a2;
        #pragma unroll
        for (int m2 = 32; m2; m2 >>= 1) {
            s0 += __shfl_xor(s0, m2, 64);
            s1 += __shfl_xor(s1, m2, 64);
            s2 += __shfl_xor(s2, m2, 64);
        }
        if (tid == 0) {
            atomicAdd(&sa[b*NK + 0], s0);
            atomicAdd(&sa[b*NK + 1], s1);
            atomicAdd(&sa[b*NK + 2], s2);
        }
    }
    __syncthreads();   // a_sh ready

    // ---- Phase B: pool straight from the register-held x ----
    float ar[NK][4];
    #pragma unroll
    for (int k = 0; k < NK; ++k)
        #pragma unroll
        for (int j = 0; j < 4; ++j) ar[k][j] = a_sh[k][4*pq + j];

    float q[16][NK];
    #pragma unroll
    for (int i = 0; i < 16; ++i) {
        const float4 v = xv[i];
        q[i][0] = fmaf(ar[0][0], v.x, fmaf(ar[0][1], v.y, fmaf(ar[0][2], v.z, ar[0][3]*v.w)));
        q[i][1] = fmaf(ar[1][0], v.x, fmaf(ar[1][1], v.y, fmaf(ar[1][2], v.z, ar[1][3]*v.w)));
        q[i][2] = fmaf(ar[2][0], v.x, fmaf(ar[2][1], v.y, fmaf(ar[2][2], v.z, ar[2][3]*v.w)));
    }

    // ---- reduce-scatter over the 16-lane pq-group (masks 1,2,4,8 stay
    //      within the group). After step s, slot j holds channel
    //      i = j*2^s + (pq & (2^s-1)); finally lane pq holds i = pq. ----
    const bool b0 = (pq & 1) != 0;
    float c1v[8][NK];
    #pragma unroll
    for (int u = 0; u < 8; ++u)
        #pragma unroll
        for (int k = 0; k < NK; ++k) {
            const float send = b0 ? q[2*u][k]   : q[2*u+1][k];
            const float keep = b0 ? q[2*u+1][k] : q[2*u][k];
            c1v[u][k] = keep + __shfl_xor(send, 1, 64);
        }
    const bool b1 = (pq & 2) != 0;
    float c2v[4][NK];
    #pragma unroll
    for (int u = 0; u < 4; ++u)
        #pragma unroll
        for (int k = 0; k < NK; ++k) {
            const float send = b1 ? c1v[2*u][k]   : c1v[2*u+1][k];
            const float keep = b1 ? c1v[2*u+1][k] : c1v[2*u][k];
            c2v[u][k] = keep + __shfl_xor(send, 2, 64);
        }
    const bool b2 = (pq & 4) != 0;
    float c3v[2][NK];
    #pragma unroll
    for (int u = 0; u < 2; ++u)
        #pragma unroll
        for (int k = 0; k < NK; ++k) {
            const float send = b2 ? c2v[2*u][k]   : c2v[2*u+1][k];
            const float keep = b2 ? c2v[2*u+1][k] : c2v[2*u][k];
            c3v[u][k] = keep + __shfl_xor(send, 4, 64);
        }
    const bool b3 = (pq & 8) != 0;
    float r[NK];
    #pragma unroll
    for (int k = 0; k < NK; ++k) {
        const float send = b3 ? c3v[0][k] : c3v[1][k];
        const float keep = b3 ? c3v[1][k] : c3v[0][k];
        r[k] = keep + __shfl_xor(send, 8, 64);
    }

    // lane (pq,cc) now holds totals for channel c_out = 16*pq + cc
    const int c_out = 16*pq + cc;
    float* qb = qx + (size_t)b * NK * CH + c_out;
    atomicAdd(qb,        r[0]);
    atomicAdd(qb + CH,   r[1]);
    atomicAdd(qb + 2*CH, r[2]);
}

// ---------------------------------------------------------------------------
// Finalize: qx/sum_ass, subtract centers, /sigma, L2-normalize over channels,
// transposed store to outputs[b][c][k].
// ---------------------------------------------------------------------------
__global__ __launch_bounds__(256)
void pgn_final(const float* __restrict__ qx,       // [BS][NK][CH]
               const float* __restrict__ sa,       // [BS][NK]
               const float* __restrict__ centers,  // [NK][CH]
               const float* __restrict__ psf,      // [NK]
               float* __restrict__ out)            // [BS][CH][NK]
{
    const int b = blockIdx.x;
    const int c = threadIdx.x;
    const int wave = c >> 6, lane = c & 63;
    __shared__ float red[4][NK];
    __shared__ float nrm[NK];

    float v[NK], ss[NK];
    #pragma unroll
    for (int k = 0; k < NK; ++k) {
        const float beta = 1.f / (1.f + __expf(-psf[k]));
        const float sig  = sqrtf(0.5f * beta);
        const float s    = fmaxf(sa[b*NK + k], 1e-5f);
        const float q    = qx[((size_t)b*NK + k)*CH + c] / s;
        v[k]  = (q - centers[k*CH + c]) / sig;
        ss[k] = v[k] * v[k];
    }
    #pragma unroll
    for (int m = 32; m; m >>= 1) {
        ss[0] += __shfl_xor(ss[0], m, 64);
        ss[1] += __shfl_xor(ss[1], m, 64);
        ss[2] += __shfl_xor(ss[2], m, 64);
    }
    if (lane == 0) { red[wave][0] = ss[0]; red[wave][1] = ss[1]; red[wave][2] = ss[2]; }
    __syncthreads();
    if (c < NK) {
        const float tot = red[0][c] + red[1][c] + red[2][c] + red[3][c];
        nrm[c] = fmaxf(sqrtf(tot), 1e-12f);
    }
    __syncthreads();
    float* o = out + ((size_t)b*CH + c)*NK;
    #pragma unroll
    for (int k = 0; k < NK; ++k) o[k] = v[k] / nrm[k];
}

// ---------------------------------------------------------------------------
extern "C" void kernel_launch(void* const* d_in, const int* in_sizes, int n_in,
                              void* d_out, int out_size, void* d_ws, size_t ws_size,
                              hipStream_t stream)
{
    const float* feat    = (const float*)d_in[0];
    const float* centers = (const float*)d_in[1];
    const float* psf     = (const float*)d_in[2];

    float* out        = (float*)d_out;            // [BS][CH][NK] first
    float* assign_out = out + (size_t)BS*CH*NK;   // then [BS][NK][NPIX]

    float* sa = (float*)d_ws + WS_SA;             // [BS][NK]
    float* qx = (float*)d_ws + WS_QX;             // [BS][NK][CH]

    // zero the atomic accumulators (ws is poisoned 0xAA before every launch)
    hipMemsetAsync(d_ws, 0, (BS*NK + BS*NK*CH) * sizeof(float), stream);

    pgn_main<<<dim3(BS*NT), dim3(256), 0, stream>>>(
        feat, centers, psf, assign_out, sa, qx);

    pgn_final<<<dim3(BS), dim3(256), 0, stream>>>(qx, sa, centers, psf, out);
}